// Round 18
// baseline (65.547 us; speedup 1.0000x reference)
//
#include <hip/hip_runtime.h>

// Chamfer min-matching loss, B=8, P=4096, D=2, fp32 — exact NN via x-sorted
// rank-window scan + wave-cooperative rescue, SINGLE DISPATCH.
// Blocks 0..15: counting-sort (batch,side) by x-bin (R16 xSort body) ->
//   publish P/BS -> __threadfence + agent-release MAGIC flag.
// Blocks 16..271: spin (s_sleep) on flag[0] & flag[qside] & flag[tgt] with
//   agent-acquire, then R16 winSearch verbatim (stage 36KB, fixed 256-cand
//   window, certificate, wave-cooperative rescue), atomicAdd(out).
// Replay-safe flag protocol: poison 0xAA != MAGIC; last searcher (fc==255)
//   resets flags+fc to 0; block 0 zeroes out+fc before releasing flag[0].
// No deadlock: 272 blocks all co-resident (40KB LDS -> >=2 blocks/CU cap).
// R17 lesson: one variable per round; both R17 changes reverted.

#define NB    8
#define NP    4096
#define XBINS 2048
#define W     0.0048828125f      // 10 / 2048
#define XMIN  -5.0f
#define INVW  204.8f
#define BSSTR (XBINS + 4)
#define WH    128                // half-window (256 candidates)
#define MAGIC 0x5AFE5AFEu

__device__ __forceinline__ int xbin(float x) {
    int i = (int)((x - XMIN) * INVW);
    return i < 0 ? 0 : (i > XBINS - 1 ? XBINS - 1 : i);
}

#define FOREACH8(M) M(0) M(1) M(2) M(3) M(4) M(5) M(6) M(7)

__global__ __launch_bounds__(256) void fusedSS(const float* __restrict__ pred,
                                               const float* __restrict__ gt,
                                               float2* __restrict__ P,
                                               unsigned* __restrict__ BS,
                                               unsigned* __restrict__ flags,
                                               unsigned* __restrict__ fc,
                                               float* __restrict__ out) {
    __shared__ __align__(16) unsigned char smem[41024];
    float2* sp = (float2*)smem;                          // 32 KB (both roles)

    int t   = threadIdx.x;
    int bid = blockIdx.x;

    if (bid < 16) {
        // ================= SORTER (R16 xSort body) =================
        unsigned* cnt     = (unsigned*)(smem + 32768);   // 8 KB
        unsigned* waveTot = (unsigned*)(smem + 40960);   // 32 B

        int s = bid, b = s >> 1, side = s & 1;

        if (s == 0 && t == 0) {
            __hip_atomic_store(out, 0.0f, __ATOMIC_RELAXED, __HIP_MEMORY_SCOPE_AGENT);
            __hip_atomic_store(fc, 0u,   __ATOMIC_RELAXED, __HIP_MEMORY_SCOPE_AGENT);
        }

        const float2* src = (const float2*)(side ? gt : pred) + (size_t)b * NP;
        float2*   dst = P  + (size_t)s * NP;
        unsigned* bs  = BS + (size_t)s * BSSTR;

#pragma unroll
        for (int i = 0; i < 8; ++i) cnt[t + i * 256] = 0;
        __syncthreads();

        const float4* src4 = (const float4*)src;
#define DECLV(i) float4 v##i = src4[t + (i) * 256]; \
        atomicAdd(&cnt[xbin(v##i.x)], 1u); atomicAdd(&cnt[xbin(v##i.z)], 1u);
        FOREACH8(DECLV)
#undef DECLV
        __syncthreads();

        unsigned local = 0;
#pragma unroll
        for (int i = 0; i < 8; ++i) local += cnt[t * 8 + i];
        unsigned inc = local;
#pragma unroll
        for (int o = 1; o < 64; o <<= 1) {
            unsigned n = __shfl_up(inc, o, 64);
            if ((t & 63) >= o) inc += n;
        }
        if ((t & 63) == 63) waveTot[t >> 6] = inc;
        __syncthreads();
        unsigned wbase = 0;
#pragma unroll
        for (int w = 0; w < 4; ++w) if (w < (t >> 6)) wbase += waveTot[w];
        unsigned run = wbase + inc - local;
#pragma unroll
        for (int i = 0; i < 8; ++i) {
            unsigned c = cnt[t * 8 + i];
            cnt[t * 8 + i] = run;
            run += c;
        }
        __syncthreads();

        for (int i = t; i < XBINS; i += 256) bs[i] = cnt[i];
        __syncthreads();

#define SCAT(i) { \
        unsigned p0 = atomicAdd(&cnt[xbin(v##i.x)], 1u); \
        sp[p0] = (float2){v##i.x, v##i.y}; \
        unsigned p1 = atomicAdd(&cnt[xbin(v##i.z)], 1u); \
        sp[p1] = (float2){v##i.z, v##i.w}; }
        FOREACH8(SCAT)
#undef SCAT
        __syncthreads();

        const float4* sp4  = (const float4*)sp;
        float4*       dst4 = (float4*)dst;
#pragma unroll
        for (int i = 0; i < 8; ++i) dst4[t + i * 256] = sp4[t + i * 256];

        __syncthreads();      // all threads' global stores issued+waited
        __threadfence();      // device-scope visibility
        if (t == 0)
            __hip_atomic_store(&flags[s], MAGIC, __ATOMIC_RELEASE, __HIP_MEMORY_SCOPE_AGENT);

    } else {
        // ================= SEARCHER (R16 winSearch body) =================
        unsigned short* sbs  = (unsigned short*)(smem + 32768);  // 4 KB
        float*          wsum = (float*)(smem + 40960);

        int sid   = bid - 16;
        int qs    = sid & 15;
        int slice = sid >> 4;
        int b = qs & 7, dir = qs >> 3;
        int qside = b * 2 + dir;
        int tgt   = b * 2 + (1 - dir);

        // spin until producer flags set (bounded: bug -> wrong result, not hang)
        if (t == 0) {
            long cap = 50000000;
            while ((__hip_atomic_load(&flags[0],     __ATOMIC_ACQUIRE, __HIP_MEMORY_SCOPE_AGENT) != MAGIC ||
                    __hip_atomic_load(&flags[qside], __ATOMIC_ACQUIRE, __HIP_MEMORY_SCOPE_AGENT) != MAGIC ||
                    __hip_atomic_load(&flags[tgt],   __ATOMIC_ACQUIRE, __HIP_MEMORY_SCOPE_AGENT) != MAGIC) && --cap)
                __builtin_amdgcn_s_sleep(1);
            __threadfence();
        }
        __syncthreads();

        const float2*   tp = P  + (size_t)tgt * NP;
        const unsigned* bs = BS + (size_t)tgt * BSSTR;

        const float4* tp4  = (const float4*)tp;
        float4*       sp4w = (float4*)sp;
#pragma unroll
        for (int i = 0; i < 8; ++i) sp4w[t + i * 256] = tp4[t + i * 256];
        const uint4* bs4  = (const uint4*)bs;
        uint2*       sbs2 = (uint2*)sbs;
#pragma unroll
        for (int i = 0; i < 2; ++i) {
            uint4 v = bs4[t + i * 256];
            sbs2[t + i * 256] = make_uint2(v.x | (v.y << 16), v.z | (v.w << 16));
        }

        const float2* qarr = P + (size_t)qside * NP;
        float2 q = qarr[slice * 256 + t];
        __syncthreads();

        float qx = q.x, qy = q.y;
        int r0 = (int)sbs[xbin(qx)];

        int w0 = r0 - WH;
        if (w0 < 0) w0 = 0;
        if (w0 > NP - 2 * WH) w0 = NP - 2 * WH;
        w0 &= ~1;

        float best = 3.402823466e+38f;
        const float4* spc = (const float4*)sp;
        int base = w0 >> 1;
#pragma unroll 8
        for (int k = 0; k < WH; ++k) {
            float4 v = spc[base + k];
            float dx0 = qx - v.x, dy0 = qy - v.y;
            float dx1 = qx - v.z, dy1 = qy - v.w;
            float d0 = fmaf(dx0, dx0, dy0 * dy0);
            float d1 = fmaf(dx1, dx1, dy1 * dy1);
            best = fminf(fminf(best, d0), d1);   // v_min3_f32
        }

        float lbL = (w0 > 0)           ? fmaxf(qx - sp[w0].x - W, 0.0f)              : 3.0e38f;
        float lbR = (w0 + 2 * WH < NP) ? fmaxf(sp[w0 + 2 * WH - 1].x - W - qx, 0.0f) : 3.0e38f;
        bool uncert = (lbL * lbL < best) || (lbR * lbR < best);

        unsigned long long mask = __ballot(uncert);
        int lane = t & 63;
        while (mask) {
            int l = __ffsll((long long)mask) - 1;
            mask &= mask - 1;
            float qlx = __shfl(qx, l, 64);
            float qly = __shfl(qy, l, 64);
            float rb = 3.402823466e+38f;
#pragma unroll 4
            for (int i = 0; i < 32; ++i) {
                float4 v = spc[lane + i * 64];
                float dx0 = qlx - v.x, dy0 = qly - v.y;
                float dx1 = qlx - v.z, dy1 = qly - v.w;
                rb = fminf(rb, fmaf(dx0, dx0, dy0 * dy0));
                rb = fminf(rb, fmaf(dx1, dx1, dy1 * dy1));
            }
#pragma unroll
            for (int o = 32; o > 0; o >>= 1) rb = fminf(rb, __shfl_xor(rb, o, 64));
            if (lane == l) best = rb;
        }

        float v = sqrtf(fmaxf(best, 1e-12f));
#pragma unroll
        for (int o = 32; o > 0; o >>= 1) v += __shfl_down(v, o, 64);
        if (lane == 0) wsum[t >> 6] = v;
        __syncthreads();
        if (t == 0) {
            atomicAdd(out, ((wsum[0] + wsum[1]) + (wsum[2] + wsum[3])) *
                               (0.5f / (float)(NB * NP)));
            unsigned old = atomicAdd(fc, 1u);
            if (old == 255u) {               // last searcher: reset protocol state
#pragma unroll
                for (int j = 0; j < 16; ++j)
                    __hip_atomic_store(&flags[j], 0u, __ATOMIC_RELAXED, __HIP_MEMORY_SCOPE_AGENT);
                __hip_atomic_store(fc, 0u, __ATOMIC_RELAXED, __HIP_MEMORY_SCOPE_AGENT);
            }
        }
    }
}

extern "C" void kernel_launch(void* const* d_in, const int* in_sizes, int n_in,
                              void* d_out, int out_size, void* d_ws, size_t ws_size,
                              hipStream_t stream) {
    const float* pred = (const float*)d_in[0];
    const float* gt   = (const float*)d_in[1];
    float*       out  = (float*)d_out;

    float2*   P     = (float2*)d_ws;                     // 512 KB
    unsigned* BS    = (unsigned*)(P + (size_t)16 * NP);  // 16*BSSTR u32
    unsigned* flags = BS + (size_t)16 * BSSTR;           // 16 u32
    unsigned* fc    = flags + 16;                        // 1 u32

    (void)in_sizes; (void)n_in; (void)out_size; (void)ws_size;

    fusedSS<<<272, 256, 0, stream>>>(pred, gt, P, BS, flags, fc, out);
}

// Round 19
// 33.601 us; speedup vs baseline: 1.9507x; 1.9507x over previous
//
#include <hip/hip_runtime.h>

// Chamfer min-matching loss, B=8, P=4096, D=2, fp32 — exact NN via x-sorted
// rank-window scan + wave-cooperative rescue. 2 dispatches (structural floor:
// coop launch and spin-flag fusion all failed — R5/R8/R18).
// Kernel 1 (xSort, 16 blocks): R16 verbatim. One coalesced read into NAMED
//   registers, LDS histogram + shfl scan, LDS scatter, coalesced write-out.
// Kernel 2 (winSearch v3, 256 blocks): NO LDS, NO staging, NO barrier.
//   Sorted queries -> adjacent lanes' 256-cand windows overlap ~252/256 ->
//   global f4 window reads are L1-broadcast. Certificate endpoints are the
//   first/last loaded f4 (free). Rescue = wave-coop coalesced global scan.
//   Per-wave atomicAdd(out).

#define NB    8
#define NP    4096
#define XBINS 2048
#define W     0.0048828125f      // 10 / 2048
#define XMIN  -5.0f
#define INVW  204.8f
#define BSSTR (XBINS + 4)        // u32 stride, 16B-aligned
#define WH    128                // half-window (256 candidates)

__device__ __forceinline__ int xbin(float x) {
    int i = (int)((x - XMIN) * INVW);
    return i < 0 ? 0 : (i > XBINS - 1 ? XBINS - 1 : i);
}

#define FOREACH8(M) M(0) M(1) M(2) M(3) M(4) M(5) M(6) M(7)

// ---- Kernel 1: counting sort by x-bin, one block per (batch, side) ----
__global__ __launch_bounds__(256) void xSort(const float* __restrict__ pred,
                                             const float* __restrict__ gt,
                                             float2* __restrict__ P,      // [16][NP]
                                             unsigned* __restrict__ BS,   // [16][BSSTR]
                                             float* __restrict__ out) {
    __shared__ __align__(16) float2 sp[NP];     // 32 KB sorted staging
    __shared__ unsigned cnt[XBINS];             // 8 KB hist -> starts -> cursors
    __shared__ unsigned waveTot[4];

    int t = threadIdx.x;
    int s = blockIdx.x;                 // 0..15
    int b = s >> 1, side = s & 1;

    if (s == 0 && t == 0) *out = 0.0f;  // stream order: before winSearch atomics

    const float2* src = (const float2*)(side ? gt : pred) + (size_t)b * NP;
    float2*   dst = P  + (size_t)s * NP;
    unsigned* bs  = BS + (size_t)s * BSSTR;

#pragma unroll
    for (int i = 0; i < XBINS / 256; ++i) cnt[t + i * 256] = 0;
    __syncthreads();

    // one coalesced read into named registers + histogram
    const float4* src4 = (const float4*)src;
#define DECLV(i) float4 v##i = src4[t + (i) * 256]; \
    atomicAdd(&cnt[xbin(v##i.x)], 1u); atomicAdd(&cnt[xbin(v##i.z)], 1u);
    FOREACH8(DECLV)
#undef DECLV
    __syncthreads();

    // exclusive scan over 2048 bins (8 bins/thread + shfl wave scan)
    unsigned local = 0;
#pragma unroll
    for (int i = 0; i < 8; ++i) local += cnt[t * 8 + i];
    unsigned inc = local;
#pragma unroll
    for (int o = 1; o < 64; o <<= 1) {
        unsigned n = __shfl_up(inc, o, 64);
        if ((t & 63) >= o) inc += n;
    }
    if ((t & 63) == 63) waveTot[t >> 6] = inc;
    __syncthreads();
    unsigned wbase = 0;
#pragma unroll
    for (int w = 0; w < 4; ++w) if (w < (t >> 6)) wbase += waveTot[w];
    unsigned run = wbase + inc - local;
#pragma unroll
    for (int i = 0; i < 8; ++i) {
        unsigned c = cnt[t * 8 + i];
        cnt[t * 8 + i] = run;           // bin starts
        run += c;
    }
    __syncthreads();

    // publish starts (coalesced) BEFORE cursors mutate
    for (int i = t; i < XBINS; i += 256) bs[i] = cnt[i];
    __syncthreads();

    // scatter from registers into LDS sorted array (cheap random ds_write)
#define SCAT(i) { \
    unsigned p0 = atomicAdd(&cnt[xbin(v##i.x)], 1u); \
    sp[p0] = (float2){v##i.x, v##i.y}; \
    unsigned p1 = atomicAdd(&cnt[xbin(v##i.z)], 1u); \
    sp[p1] = (float2){v##i.z, v##i.w}; }
    FOREACH8(SCAT)
#undef SCAT
    __syncthreads();

    // coalesced write-out of the sorted array
    const float4* sp4 = (const float4*)sp;
    float4*       dst4 = (float4*)dst;
#pragma unroll
    for (int i = 0; i < 8; ++i) dst4[t + i * 256] = sp4[t + i * 256];
}

// ---- Kernel 2: LDS-free window scan straight from global (L1-broadcast) ----
__global__ __launch_bounds__(256) void winSearch(const float2* __restrict__ P,
                                                 const unsigned* __restrict__ BS,
                                                 float* __restrict__ out) {
    int t     = threadIdx.x;
    int bid   = blockIdx.x;        // 0..255
    int qs    = bid & 15;          // dir*8 + b
    int slice = bid >> 4;          // 0..15
    int b = qs & 7, dir = qs >> 3;

    int tgt = b * 2 + (1 - dir);   // sorted target side
    const float4*   tp4 = (const float4*)(P + (size_t)tgt * NP);
    const unsigned* bs  = BS + (size_t)tgt * BSSTR;

    // query from the SORTED query-side array (coalesced; order-invariant mean)
    const float2* qarr = P + (size_t)(b * 2 + dir) * NP;
    float2 q = qarr[slice * 256 + t];
    float qx = q.x, qy = q.y;

    // window start from global bin-start lookup (scattered dword, L2)
    int r0 = (int)bs[xbin(qx)];
    int w0 = r0 - WH;
    if (w0 < 0) w0 = 0;
    if (w0 > NP - 2 * WH) w0 = NP - 2 * WH;
    w0 &= ~1;                       // 16B-align the f4 stream
    int base = w0 >> 1;

    // fixed 256-candidate window scan from GLOBAL; adjacent lanes' windows
    // overlap ~252/256 -> L1-broadcast. Capture cert endpoints in-loop.
    float best = 3.402823466e+38f;
    float firstx = 0.0f, lastx = 0.0f;
#pragma unroll 8
    for (int k = 0; k < WH; ++k) {
        float4 v = tp4[base + k];
        if (k == 0)      firstx = v.x;   // == sorted[w0].x
        if (k == WH - 1) lastx  = v.z;   // == sorted[w0+2*WH-1].x
        float dx0 = qx - v.x, dy0 = qy - v.y;
        float dx1 = qx - v.z, dy1 = qy - v.w;
        float d0 = fmaf(dx0, dx0, dy0 * dy0);
        float d1 = fmaf(dx1, dx1, dy1 * dy1);
        best = fminf(fminf(best, d0), d1);   // v_min3_f32
    }

    // certificate (bin-sorted: rank<w0 => x <= sorted[w0].x + W, mirrored)
    float lbL = (w0 > 0)           ? fmaxf(qx - firstx - W, 0.0f) : 3.0e38f;
    float lbR = (w0 + 2 * WH < NP) ? fmaxf(lastx - W - qx, 0.0f)  : 3.0e38f;
    bool uncert = (lbL * lbL < best) || (lbR * lbR < best);

    // wave-cooperative rescue: full exact scan of GLOBAL sorted target
    unsigned long long mask = __ballot(uncert);
    int lane = t & 63;
    while (mask) {
        int l = __ffsll((long long)mask) - 1;
        mask &= mask - 1;
        float qlx = __shfl(qx, l, 64);
        float qly = __shfl(qy, l, 64);
        float rb = 3.402823466e+38f;
#pragma unroll 4
        for (int i = 0; i < 32; ++i) {      // 64 lanes x 32 f4 = all 4096
            float4 v = tp4[lane + i * 64];  // coalesced, L2-hot
            float dx0 = qlx - v.x, dy0 = qly - v.y;
            float dx1 = qlx - v.z, dy1 = qly - v.w;
            rb = fminf(rb, fmaf(dx0, dx0, dy0 * dy0));
            rb = fminf(rb, fmaf(dx1, dx1, dy1 * dy1));
        }
#pragma unroll
        for (int o = 32; o > 0; o >>= 1) rb = fminf(rb, __shfl_xor(rb, o, 64));
        if (lane == l) best = rb;
    }

    // sqrt + wave-sum + one atomicAdd per wave (no LDS, no barrier)
    float v = sqrtf(fmaxf(best, 1e-12f));
#pragma unroll
    for (int o = 32; o > 0; o >>= 1) v += __shfl_down(v, o, 64);
    if (lane == 0)
        atomicAdd(out, v * (0.5f / (float)(NB * NP)));
}

extern "C" void kernel_launch(void* const* d_in, const int* in_sizes, int n_in,
                              void* d_out, int out_size, void* d_ws, size_t ws_size,
                              hipStream_t stream) {
    const float* pred = (const float*)d_in[0];
    const float* gt   = (const float*)d_in[1];
    float*       out  = (float*)d_out;

    float2*   P  = (float2*)d_ws;                       // 16 * 4096 * 8 B = 512 KB
    unsigned* BS = (unsigned*)(P + (size_t)16 * NP);    // 16 * 2052 * 4 B

    (void)in_sizes; (void)n_in; (void)out_size; (void)ws_size;

    xSort<<<16, 256, 0, stream>>>(pred, gt, P, BS, out);
    winSearch<<<256, 256, 0, stream>>>(P, BS, out);
}

// Round 20
// 22.991 us; speedup vs baseline: 2.8510x; 1.4615x over previous
//
#include <hip/hip_runtime.h>

// Chamfer min-matching loss, B=8, P=4096, D=2, fp32 — exact NN via x-sorted
// rank-window scan + wave-cooperative rescue. 2 dispatches (structural floor;
// coop/spin fusion failed R5/R8/R18; global-scan failed R19).
// Kernel 1 (xSort, 16 blocks x 512 thr): counting-sort by x-bin. One coalesced
//   read into NAMED registers (8 pts/thread), LDS histogram + 8-wave shfl
//   scan, LDS scatter, coalesced write-out. 512 thr halves serial depth vs R16.
// Kernel 2 (winSearch, 256 blocks): R16 verbatim; stage 32KB sorted pts +
//   4KB u16 bin starts in LDS; sorted queries -> conflict-free fixed
//   256-candidate window scan; certificate endpoints captured in-loop;
//   wave-cooperative rescue for uncertified lanes (~1%).

#define NB    8
#define NP    4096
#define XBINS 2048
#define W     0.0048828125f      // 10 / 2048
#define XMIN  -5.0f
#define INVW  204.8f
#define BSSTR (XBINS + 4)        // u32 stride, 16B-aligned
#define WH    128                // half-window (256 candidates)

__device__ __forceinline__ int xbin(float x) {
    int i = (int)((x - XMIN) * INVW);
    return i < 0 ? 0 : (i > XBINS - 1 ? XBINS - 1 : i);
}

#define FOREACH4(M) M(0) M(1) M(2) M(3)

// ---- Kernel 1: counting sort by x-bin, one block per (batch, side) ----
__global__ __launch_bounds__(512) void xSort(const float* __restrict__ pred,
                                             const float* __restrict__ gt,
                                             float2* __restrict__ P,      // [16][NP]
                                             unsigned* __restrict__ BS,   // [16][BSSTR]
                                             float* __restrict__ out) {
    __shared__ __align__(16) float2 sp[NP];     // 32 KB sorted staging
    __shared__ unsigned cnt[XBINS];             // 8 KB hist -> starts -> cursors
    __shared__ unsigned waveTot[8];

    int t = threadIdx.x;
    int s = blockIdx.x;                 // 0..15
    int b = s >> 1, side = s & 1;

    if (s == 0 && t == 0) *out = 0.0f;  // stream order: before winSearch atomics

    const float2* src = (const float2*)(side ? gt : pred) + (size_t)b * NP;
    float2*   dst = P  + (size_t)s * NP;
    unsigned* bs  = BS + (size_t)s * BSSTR;

#pragma unroll
    for (int i = 0; i < XBINS / 512; ++i) cnt[t + i * 512] = 0;
    __syncthreads();

    // one coalesced read into named registers + histogram (8 pts/thread)
    const float4* src4 = (const float4*)src;    // 2048 float4
#define DECLV(i) float4 v##i = src4[t + (i) * 512]; \
    atomicAdd(&cnt[xbin(v##i.x)], 1u); atomicAdd(&cnt[xbin(v##i.z)], 1u);
    FOREACH4(DECLV)
#undef DECLV
    __syncthreads();

    // exclusive scan over 2048 bins (4 bins/thread + shfl wave scan, 8 waves)
    unsigned local = cnt[t * 4] + cnt[t * 4 + 1] + cnt[t * 4 + 2] + cnt[t * 4 + 3];
    unsigned inc = local;
#pragma unroll
    for (int o = 1; o < 64; o <<= 1) {
        unsigned n = __shfl_up(inc, o, 64);
        if ((t & 63) >= o) inc += n;
    }
    if ((t & 63) == 63) waveTot[t >> 6] = inc;
    __syncthreads();
    unsigned wbase = 0;
#pragma unroll
    for (int w = 0; w < 8; ++w) if (w < (t >> 6)) wbase += waveTot[w];
    unsigned run = wbase + inc - local;
#pragma unroll
    for (int i = 0; i < 4; ++i) {
        unsigned c = cnt[t * 4 + i];
        cnt[t * 4 + i] = run;           // bin starts
        run += c;
    }
    __syncthreads();

    // publish starts (coalesced) BEFORE cursors mutate
    for (int i = t; i < XBINS; i += 512) bs[i] = cnt[i];
    __syncthreads();

    // scatter from registers into LDS sorted array (cheap random ds_write)
#define SCAT(i) { \
    unsigned p0 = atomicAdd(&cnt[xbin(v##i.x)], 1u); \
    sp[p0] = (float2){v##i.x, v##i.y}; \
    unsigned p1 = atomicAdd(&cnt[xbin(v##i.z)], 1u); \
    sp[p1] = (float2){v##i.z, v##i.w}; }
    FOREACH4(SCAT)
#undef SCAT
    __syncthreads();

    // coalesced write-out of the sorted array
    const float4* sp4 = (const float4*)sp;
    float4*       dst4 = (float4*)dst;
#pragma unroll
    for (int i = 0; i < 4; ++i) dst4[t + i * 512] = sp4[t + i * 512];
}

// ---- Kernel 2: fixed-window scan + wave-cooperative rescue (R16 + in-loop cert) ----
__global__ __launch_bounds__(256) void winSearch(const float2* __restrict__ P,
                                                 const unsigned* __restrict__ BS,
                                                 float* __restrict__ out) {
    __shared__ __align__(16) float2 sp[NP];             // 32 KB sorted target
    __shared__ __align__(16) unsigned short sbs[XBINS]; // 4 KB bin starts

    int t     = threadIdx.x;
    int bid   = blockIdx.x;        // 0..255
    int qs    = bid & 15;          // dir*8 + b
    int slice = bid >> 4;          // 0..15
    int b = qs & 7, dir = qs >> 3;

    int tgt = b * 2 + (1 - dir);   // sorted target side
    const float2*   tp = P  + (size_t)tgt * NP;
    const unsigned* bs = BS + (size_t)tgt * BSSTR;

    // stage sorted points (32 KB) + bin starts packed to u16 (4 KB)
    const float4* tp4 = (const float4*)tp;
    float4*       sp4w = (float4*)sp;
#pragma unroll
    for (int i = 0; i < 8; ++i) sp4w[t + i * 256] = tp4[t + i * 256];
    const uint4* bs4  = (const uint4*)bs;
    uint2*       sbs2 = (uint2*)sbs;
#pragma unroll
    for (int i = 0; i < 2; ++i) {
        uint4 v = bs4[t + i * 256];
        sbs2[t + i * 256] = make_uint2(v.x | (v.y << 16), v.z | (v.w << 16));
    }

    // query from the SORTED query-side array (coalesced; order-invariant mean)
    const float2* qarr = P + (size_t)(b * 2 + dir) * NP;
    float2 q = qarr[slice * 256 + t];
    __syncthreads();

    float qx = q.x, qy = q.y;
    int r0 = (int)sbs[xbin(qx)];

    int w0 = r0 - WH;
    if (w0 < 0) w0 = 0;
    if (w0 > NP - 2 * WH) w0 = NP - 2 * WH;
    w0 &= ~1;                       // 16B-align the b128 stream

    float best = 3.402823466e+38f;
    const float4* spc = (const float4*)sp;
    int base = w0 >> 1;
    float firstx = 0.0f, lastx = 0.0f;
#pragma unroll 8
    for (int k = 0; k < WH; ++k) {  // 128 x b128 = 256 candidates, fixed trip
        float4 v = spc[base + k];
        if (k == 0)      firstx = v.x;   // sorted[w0].x
        if (k == WH - 1) lastx  = v.z;   // sorted[w0+2*WH-1].x
        float dx0 = qx - v.x, dy0 = qy - v.y;
        float dx1 = qx - v.z, dy1 = qy - v.w;
        float d0 = fmaf(dx0, dx0, dy0 * dy0);
        float d1 = fmaf(dx1, dx1, dy1 * dy1);
        best = fminf(fminf(best, d0), d1);   // v_min3_f32
    }

    // certificate (bin-sorted: rank<w0 => x <= sorted[w0].x + W, mirrored)
    float lbL = (w0 > 0)           ? fmaxf(qx - firstx - W, 0.0f) : 3.0e38f;
    float lbR = (w0 + 2 * WH < NP) ? fmaxf(lastx - W - qx, 0.0f)  : 3.0e38f;
    bool uncert = (lbL * lbL < best) || (lbR * lbR < best);

    // wave-cooperative rescue: full exact scan per uncertified lane
    unsigned long long mask = __ballot(uncert);
    int lane = t & 63;
    while (mask) {
        int l = __ffsll((long long)mask) - 1;
        mask &= mask - 1;
        float qlx = __shfl(qx, l, 64);
        float qly = __shfl(qy, l, 64);
        float rb = 3.402823466e+38f;
#pragma unroll 4
        for (int i = 0; i < 32; ++i) {      // 64 lanes x 32 x 2 pts = all 4096
            float4 v = spc[lane + i * 64];
            float dx0 = qlx - v.x, dy0 = qly - v.y;
            float dx1 = qlx - v.z, dy1 = qly - v.w;
            rb = fminf(rb, fmaf(dx0, dx0, dy0 * dy0));
            rb = fminf(rb, fmaf(dx1, dx1, dy1 * dy1));
        }
#pragma unroll
        for (int o = 32; o > 0; o >>= 1) rb = fminf(rb, __shfl_xor(rb, o, 64));
        if (lane == l) best = rb;           // exact full-scan result
    }

    float v = sqrtf(fmaxf(best, 1e-12f));

#pragma unroll
    for (int o = 32; o > 0; o >>= 1) v += __shfl_down(v, o, 64);

    __shared__ float wsum[4];
    if ((t & 63) == 0) wsum[t >> 6] = v;
    __syncthreads();
    if (t == 0)
        atomicAdd(out, ((wsum[0] + wsum[1]) + (wsum[2] + wsum[3])) *
                           (0.5f / (float)(NB * NP)));
}

extern "C" void kernel_launch(void* const* d_in, const int* in_sizes, int n_in,
                              void* d_out, int out_size, void* d_ws, size_t ws_size,
                              hipStream_t stream) {
    const float* pred = (const float*)d_in[0];
    const float* gt   = (const float*)d_in[1];
    float*       out  = (float*)d_out;

    float2*   P  = (float2*)d_ws;                       // 16 * 4096 * 8 B = 512 KB
    unsigned* BS = (unsigned*)(P + (size_t)16 * NP);    // 16 * 2052 * 4 B

    (void)in_sizes; (void)n_in; (void)out_size; (void)ws_size;

    xSort<<<16, 512, 0, stream>>>(pred, gt, P, BS, out);
    winSearch<<<256, 256, 0, stream>>>(P, BS, out);
}

// Round 21
// 22.625 us; speedup vs baseline: 2.8970x; 1.0162x over previous
//
#include <hip/hip_runtime.h>

// Chamfer min-matching loss, B=8, P=4096, D=2, fp32 — exact NN via x-sorted
// rank-window scan + wave-cooperative rescue. FINAL: R16 configuration
// verbatim (best measured: 22.6 us).
// Kernel 1 (xSort, 16 blocks x 256 thr): counting-sort each (batch,side) by
//   x-bin. One coalesced read into NAMED registers, LDS histogram + shfl
//   scan, LDS scatter (cheap random ds_write), coalesced write-out.
// Kernel 2 (winSearch, 256 blocks): stage 32KB sorted pts + 4KB u16 bin
//   starts in LDS. Queries from the SORTED query-side array (order-invariant
//   mean) -> adjacent lanes adjacent ranks -> conflict-free fixed
//   256-candidate window scan; x-distance certificate; uncertified lanes
//   (~1%) rescued by wave-cooperative full LDS scan.
// Structural floor: 2 dispatches x ~6.5us overhead + ~6.5us kernels.
// Excluded by measurement: coop launch (R5:357, R8:215), spin-flags (R18:66),
// self-sort/block (R15:33), global-scan (R19:34), banded staging (R17:27),
// 512-thr sort (R20:23.0), brute force best (R6:29.1).

#define NB    8
#define NP    4096
#define XBINS 2048
#define W     0.0048828125f      // 10 / 2048
#define XMIN  -5.0f
#define INVW  204.8f
#define BSSTR (XBINS + 4)        // u32 stride, 16B-aligned
#define WH    128                // half-window (256 candidates)

__device__ __forceinline__ int xbin(float x) {
    int i = (int)((x - XMIN) * INVW);
    return i < 0 ? 0 : (i > XBINS - 1 ? XBINS - 1 : i);
}

#define FOREACH8(M) M(0) M(1) M(2) M(3) M(4) M(5) M(6) M(7)

// ---- Kernel 1: counting sort by x-bin, one block per (batch, side) ----
__global__ __launch_bounds__(256) void xSort(const float* __restrict__ pred,
                                             const float* __restrict__ gt,
                                             float2* __restrict__ P,      // [16][NP]
                                             unsigned* __restrict__ BS,   // [16][BSSTR]
                                             float* __restrict__ out) {
    __shared__ __align__(16) float2 sp[NP];     // 32 KB sorted staging
    __shared__ unsigned cnt[XBINS];             // 8 KB hist -> starts -> cursors
    __shared__ unsigned waveTot[4];

    int t = threadIdx.x;
    int s = blockIdx.x;                 // 0..15
    int b = s >> 1, side = s & 1;

    if (s == 0 && t == 0) *out = 0.0f;  // stream order: before winSearch atomics

    const float2* src = (const float2*)(side ? gt : pred) + (size_t)b * NP;
    float2*   dst = P  + (size_t)s * NP;
    unsigned* bs  = BS + (size_t)s * BSSTR;

#pragma unroll
    for (int i = 0; i < XBINS / 256; ++i) cnt[t + i * 256] = 0;
    __syncthreads();

    // one coalesced read into named registers + histogram
    const float4* src4 = (const float4*)src;
#define DECLV(i) float4 v##i = src4[t + (i) * 256]; \
    atomicAdd(&cnt[xbin(v##i.x)], 1u); atomicAdd(&cnt[xbin(v##i.z)], 1u);
    FOREACH8(DECLV)
#undef DECLV
    __syncthreads();

    // exclusive scan over 2048 bins (8 bins/thread + shfl wave scan)
    unsigned local = 0;
#pragma unroll
    for (int i = 0; i < 8; ++i) local += cnt[t * 8 + i];
    unsigned inc = local;
#pragma unroll
    for (int o = 1; o < 64; o <<= 1) {
        unsigned n = __shfl_up(inc, o, 64);
        if ((t & 63) >= o) inc += n;
    }
    if ((t & 63) == 63) waveTot[t >> 6] = inc;
    __syncthreads();
    unsigned wbase = 0;
#pragma unroll
    for (int w = 0; w < 4; ++w) if (w < (t >> 6)) wbase += waveTot[w];
    unsigned run = wbase + inc - local;
#pragma unroll
    for (int i = 0; i < 8; ++i) {
        unsigned c = cnt[t * 8 + i];
        cnt[t * 8 + i] = run;           // bin starts
        run += c;
    }
    __syncthreads();

    // publish starts (coalesced) BEFORE cursors mutate
    for (int i = t; i < XBINS; i += 256) bs[i] = cnt[i];
    __syncthreads();

    // scatter from registers into LDS sorted array (cheap random ds_write)
#define SCAT(i) { \
    unsigned p0 = atomicAdd(&cnt[xbin(v##i.x)], 1u); \
    sp[p0] = (float2){v##i.x, v##i.y}; \
    unsigned p1 = atomicAdd(&cnt[xbin(v##i.z)], 1u); \
    sp[p1] = (float2){v##i.z, v##i.w}; }
    FOREACH8(SCAT)
#undef SCAT
    __syncthreads();

    // coalesced write-out of the sorted array
    const float4* sp4 = (const float4*)sp;
    float4*       dst4 = (float4*)dst;
#pragma unroll
    for (int i = 0; i < 8; ++i) dst4[t + i * 256] = sp4[t + i * 256];
}

// ---- Kernel 2: fixed-window scan + wave-cooperative rescue ----
__global__ __launch_bounds__(256) void winSearch(const float2* __restrict__ P,
                                                 const unsigned* __restrict__ BS,
                                                 float* __restrict__ out) {
    __shared__ __align__(16) float2 sp[NP];             // 32 KB sorted target
    __shared__ __align__(16) unsigned short sbs[XBINS]; // 4 KB bin starts

    int t     = threadIdx.x;
    int bid   = blockIdx.x;        // 0..255
    int qs    = bid & 15;          // dir*8 + b
    int slice = bid >> 4;          // 0..15
    int b = qs & 7, dir = qs >> 3;

    int tgt = b * 2 + (1 - dir);   // sorted target side
    const float2*   tp = P  + (size_t)tgt * NP;
    const unsigned* bs = BS + (size_t)tgt * BSSTR;

    // stage sorted points (32 KB) + bin starts packed to u16 (4 KB)
    const float4* tp4 = (const float4*)tp;
    float4*       sp4w = (float4*)sp;
#pragma unroll
    for (int i = 0; i < 8; ++i) sp4w[t + i * 256] = tp4[t + i * 256];
    const uint4* bs4  = (const uint4*)bs;
    uint2*       sbs2 = (uint2*)sbs;
#pragma unroll
    for (int i = 0; i < 2; ++i) {
        uint4 v = bs4[t + i * 256];
        sbs2[t + i * 256] = make_uint2(v.x | (v.y << 16), v.z | (v.w << 16));
    }

    // query from the SORTED query-side array (coalesced; order-invariant mean)
    const float2* qarr = P + (size_t)(b * 2 + dir) * NP;
    float2 q = qarr[slice * 256 + t];
    __syncthreads();

    float qx = q.x, qy = q.y;
    int r0 = (int)sbs[xbin(qx)];

    int w0 = r0 - WH;
    if (w0 < 0) w0 = 0;
    if (w0 > NP - 2 * WH) w0 = NP - 2 * WH;
    w0 &= ~1;                       // 16B-align the b128 stream

    float best = 3.402823466e+38f;
    const float4* spc = (const float4*)sp;
    int base = w0 >> 1;
#pragma unroll 8
    for (int k = 0; k < WH; ++k) {  // 128 x b128 = 256 candidates, fixed trip
        float4 v = spc[base + k];
        float dx0 = qx - v.x, dy0 = qy - v.y;
        float dx1 = qx - v.z, dy1 = qy - v.w;
        float d0 = fmaf(dx0, dx0, dy0 * dy0);
        float d1 = fmaf(dx1, dx1, dy1 * dy1);
        best = fminf(fminf(best, d0), d1);   // v_min3_f32
    }

    // certificate (bin-sorted: k<w0 => p.x <= sp[w0].x + W, mirrored)
    float lbL = (w0 > 0)           ? fmaxf(qx - sp[w0].x - W, 0.0f)              : 3.0e38f;
    float lbR = (w0 + 2 * WH < NP) ? fmaxf(sp[w0 + 2 * WH - 1].x - W - qx, 0.0f) : 3.0e38f;
    bool uncert = (lbL * lbL < best) || (lbR * lbR < best);

    // wave-cooperative rescue: full exact scan per uncertified lane
    unsigned long long mask = __ballot(uncert);
    int lane = t & 63;
    while (mask) {
        int l = __ffsll((long long)mask) - 1;
        mask &= mask - 1;
        float qlx = __shfl(qx, l, 64);
        float qly = __shfl(qy, l, 64);
        float rb = 3.402823466e+38f;
#pragma unroll 4
        for (int i = 0; i < 32; ++i) {      // 64 lanes x 32 x 2 pts = all 4096
            float4 v = spc[lane + i * 64];
            float dx0 = qlx - v.x, dy0 = qly - v.y;
            float dx1 = qlx - v.z, dy1 = qly - v.w;
            rb = fminf(rb, fmaf(dx0, dx0, dy0 * dy0));
            rb = fminf(rb, fmaf(dx1, dx1, dy1 * dy1));
        }
#pragma unroll
        for (int o = 32; o > 0; o >>= 1) rb = fminf(rb, __shfl_xor(rb, o, 64));
        if (lane == l) best = rb;           // exact full-scan result
    }

    float v = sqrtf(fmaxf(best, 1e-12f));

#pragma unroll
    for (int o = 32; o > 0; o >>= 1) v += __shfl_down(v, o, 64);

    __shared__ float wsum[4];
    if ((t & 63) == 0) wsum[t >> 6] = v;
    __syncthreads();
    if (t == 0)
        atomicAdd(out, ((wsum[0] + wsum[1]) + (wsum[2] + wsum[3])) *
                           (0.5f / (float)(NB * NP)));
}

extern "C" void kernel_launch(void* const* d_in, const int* in_sizes, int n_in,
                              void* d_out, int out_size, void* d_ws, size_t ws_size,
                              hipStream_t stream) {
    const float* pred = (const float*)d_in[0];
    const float* gt   = (const float*)d_in[1];
    float*       out  = (float*)d_out;

    float2*   P  = (float2*)d_ws;                       // 16 * 4096 * 8 B = 512 KB
    unsigned* BS = (unsigned*)(P + (size_t)16 * NP);    // 16 * 2052 * 4 B

    (void)in_sizes; (void)n_in; (void)out_size; (void)ws_size;

    xSort<<<16, 256, 0, stream>>>(pred, gt, P, BS, out);
    winSearch<<<256, 256, 0, stream>>>(P, BS, out);
}